// Round 5
// baseline (457.381 us; speedup 1.0000x reference)
//
#include <hip/hip_runtime.h>

// VectorQuantizer: x (64,64,64,64) f32, embeddings (64,512) f32
// rows N = 64^3 = 262144, D = 64, K = 512
// out: quantized_st (16777216 f32) ++ loss (1 f32)
//
// Round 5: fp16 2-term-split MFMA (A = z_hi+z_lo fp16, B = e_hi fp16;
// error eps_d <= ~9e-4 worst) computes approximate distances; per-row top-2
// masked keys flag near-ties (12-grid-step window >= 2.44e-3 coverage >
// 1.8e-3 worst differential error); fixup kernel re-resolves flagged rows
// (~10k) with the bit-exact numpy emulation (verified absmax 0.0 in r2-r4).
// Fixup's round-4 scratch-spill bug (dynamic z[i] indexing) fixed by full
// unroll. vq_main: no LDS, B-frags from L1/L2-hot global, 256-thread blocks.

typedef __attribute__((ext_vector_type(8))) _Float16 f16x8;
typedef __attribute__((ext_vector_type(16))) float f32x16;

#define NROWS   262144
#define DIM     64
#define KCODES  512
#define NELEM   16777216
#define LISTCAP 65536

// ws layout (float offsets)
#define WS_ET     0        // 512*64 code-major embeddings
#define WS_EN     32768    // exact enorm (numpy rounding)
#define WS_EN8    33280    // enorm + 8 (approx domain, keeps d positive)
#define WS_PACKH  33792    // uint4[4096]: e_hi fp16 B-fragments
#define WS_CNT    50176    // flag counter (int)
#define WS_LIST   50192    // flagged rows: (row<<9)|idx

union FragH { uint4 q; f16x8 v; _Float16 u[8]; };

// ---- prep: ET transpose, exact enorm (R(e*e) + sequential adds), enorm+8,
// zero loss + flag counter.
__global__ void vq_prep(const float* __restrict__ E, float* __restrict__ ET,
                        float* __restrict__ en, float* __restrict__ en8,
                        float* __restrict__ loss, int* __restrict__ cnt) {
    int k = blockIdx.x * blockDim.x + threadIdx.x;   // 0..511
    if (k == 0) *loss = 0.f;
    if (k == 1) *cnt = 0;
    float s = 0.f;
    for (int i = 0; i < DIM; ++i) {
        float v = E[i * KCODES + k];
        ET[k * DIM + i] = v;
        s = __fadd_rn(s, __fmul_rn(v, v));
    }
    en[k] = s;
    en8[k] = __fadd_rn(s, 8.0f);
}

// ---- pack e_hi (fp16 RNE) into 32x32x16 B-fragment order:
// frag id = (t*4+c)*64+lane holds B[k = c*16+(lane>>5)*8+j][n = t*32+(lane&31)]
__global__ void vq_pack(const float* __restrict__ E, uint4* __restrict__ packH) {
    const int id = blockIdx.x * 256 + threadIdx.x;   // 0..4095
    const int lane = id & 63;
    const int c = (id >> 6) & 3;
    const int t = id >> 8;
    const int n = t * 32 + (lane & 31);
    const int kb = c * 16 + (lane >> 5) * 8;
    FragH H;
    #pragma unroll
    for (int j = 0; j < 8; ++j)
        H.u[j] = (_Float16)E[(size_t)(kb + j) * KCODES + n];
    packH[id] = H.q;
}

// ---- main: 4 waves x 64 rows = 256 rows/block, grid 1024. No LDS.
// Each wave: two 32x32 M-tiles over 16 col-tiles; 16 MFMA per tile-pair
// (zh*eh + zl*eh, fp16 32x32x16).
__global__ __launch_bounds__(256)
void vq_main(const float* __restrict__ x, const float* __restrict__ ET,
             const float* __restrict__ en8, const uint4* __restrict__ packH,
             float* __restrict__ outp, float* __restrict__ loss,
             int* __restrict__ cnt, int* __restrict__ list) {
    const int tid  = threadIdx.x;
    const int wv   = tid >> 6;
    const int lane = tid & 63;
    const int h    = lane >> 5;
    const int l31  = lane & 31;
    const size_t rowbase = (size_t)blockIdx.x * 256 + (size_t)wv * 64;

    // A fragments: fp16 split z = zh + zl; A[m=lane&31][k=c*16+h*8+j]
    FragH ah[2][4], al[2][4];
    #pragma unroll
    for (int m = 0; m < 2; ++m) {
        const float* xr = x + (rowbase + m * 32 + l31) * DIM;
        #pragma unroll
        for (int c = 0; c < 4; ++c) {
            const float* xp = xr + c * 16 + h * 8;
            float4 p0 = *(const float4*)xp;
            float4 p1 = *(const float4*)(xp + 4);
            float vv[8] = {p0.x, p0.y, p0.z, p0.w, p1.x, p1.y, p1.z, p1.w};
            #pragma unroll
            for (int j = 0; j < 8; ++j) {
                _Float16 hh = (_Float16)vv[j];
                ah[m][c].u[j] = hh;
                al[m][c].u[j] = (_Float16)(vv[j] - (float)hh);
            }
        }
    }

    float en8v[16];
    #pragma unroll
    for (int t = 0; t < 16; ++t) en8v[t] = en8[t * 32 + l31];

    unsigned int b1[2][16], b2[2][16];               // per-row-slot top-2 keys
    #pragma unroll
    for (int m = 0; m < 2; ++m)
        #pragma unroll
        for (int r = 0; r < 16; ++r) { b1[m][r] = 0xFFFFFFFFu; b2[m][r] = 0xFFFFFFFFu; }

    for (int t = 0; t < 16; ++t) {
        FragH bh[4];
        #pragma unroll
        for (int c = 0; c < 4; ++c)
            bh[c].q = packH[(t * 4 + c) * 64 + lane];   // coalesced, L1/L2-hot
        f32x16 A0, A1;
        #pragma unroll
        for (int r = 0; r < 16; ++r) { A0[r] = 0.f; A1[r] = 0.f; }
        #pragma unroll
        for (int c = 0; c < 4; ++c) {                    // z_hi * e_hi
            A0 = __builtin_amdgcn_mfma_f32_32x32x16_f16(ah[0][c].v, bh[c].v, A0, 0, 0, 0);
            A1 = __builtin_amdgcn_mfma_f32_32x32x16_f16(ah[1][c].v, bh[c].v, A1, 0, 0, 0);
        }
        #pragma unroll
        for (int c = 0; c < 4; ++c) {                    // z_lo * e_hi
            A0 = __builtin_amdgcn_mfma_f32_32x32x16_f16(al[0][c].v, bh[c].v, A0, 0, 0, 0);
            A1 = __builtin_amdgcn_mfma_f32_32x32x16_f16(al[1][c].v, bh[c].v, A1, 0, 0, 0);
        }
        // keys: d = enorm+8 - 2*sim > 0; (bits & ~511) | col sorts by dist
        const unsigned int colv = (unsigned int)(t * 32 + l31);
        #pragma unroll
        for (int r = 0; r < 16; ++r) {
            {
                float d = fmaf(-2.f, A0[r], en8v[t]);
                unsigned int key = (__float_as_uint(d) & 0xFFFFFE00u) | colv;
                unsigned int n1 = min(key, b1[0][r]);
                unsigned int mx = max(key, b1[0][r]);
                b2[0][r] = min(b2[0][r], mx);
                b1[0][r] = n1;
            }
            {
                float d = fmaf(-2.f, A1[r], en8v[t]);
                unsigned int key = (__float_as_uint(d) & 0xFFFFFE00u) | colv;
                unsigned int n1 = min(key, b1[1][r]);
                unsigned int mx = max(key, b1[1][r]);
                b2[1][r] = min(b2[1][r], mx);
                b1[1][r] = n1;
            }
        }
    }

    // merge top-2 across the 32-lane half-group; C row = (r&3)+8*(r>>2)+4*h
    float lsq = 0.f;
    #pragma unroll
    for (int m = 0; m < 2; ++m) {
        #pragma unroll
        for (int r = 0; r < 16; ++r) {
            unsigned int B1 = b1[m][r], B2 = b2[m][r];
            #pragma unroll
            for (int off = 1; off <= 16; off <<= 1) {
                unsigned int o1 = (unsigned int)__shfl_xor((int)B1, off, 64);
                unsigned int o2 = (unsigned int)__shfl_xor((int)B2, off, 64);
                unsigned int n1 = min(B1, o1);
                unsigned int mx = max(B1, o1);
                B2 = min(min(B2, o2), mx);
                B1 = n1;
            }
            const int idx = (int)(B1 & 511u);
            const int rowl = (r & 3) + 8 * (r >> 2) + 4 * h;
            const size_t row = rowbase + m * 32 + rowl;
            // 12-step window: min coverage (12-2)*2.44e-4 = 2.44e-3 >
            // 1.8e-3 worst-case differential approx error.
            if (l31 == 0 &&
                ((B2 & 0xFFFFFE00u) - (B1 & 0xFFFFFE00u)) <= (12u << 9)) {
                int slot = atomicAdd(cnt, 1);
                if (slot < LISTCAP)
                    list[slot] = (int)(((unsigned int)row << 9) | (unsigned int)idx);
            }
            // out = R(x + R(q - x)); 32 lanes x 2 cols cover the row
            const float2 q2 = ((const float2*)(ET + idx * DIM))[l31];
            const float2 x2 = ((const float2*)(x + row * DIM))[l31];
            float d0 = __fadd_rn(q2.x, -x2.x);
            float d1 = __fadd_rn(q2.y, -x2.y);
            float2 o;
            o.x = __fadd_rn(x2.x, d0);
            o.y = __fadd_rn(x2.y, d1);
            ((float2*)(outp + row * DIM))[l31] = o;
            lsq = fmaf(d0, d0, lsq);
            lsq = fmaf(d1, d1, lsq);
        }
    }
    #pragma unroll
    for (int off = 32; off > 0; off >>= 1) lsq += __shfl_xor(lsq, off, 64);
    if (lane == 0) atomicAdd(loss, lsq * (1.25f / (float)NELEM));
}

// ---- fixup: one wave per flagged row; full bit-exact numpy emulation over
// all 512 codes (8 codes/lane, sequential-i FMA chains), rewrite if changed.
// i-loop FULLY UNROLLED so z[] stays in VGPRs (round-4 spilled to scratch).
__global__ void vq_fixup(const float* __restrict__ x, const float* __restrict__ E,
                         const float* __restrict__ ET, const float* __restrict__ en,
                         float* __restrict__ outp, float* __restrict__ loss,
                         const int* __restrict__ cnt, const int* __restrict__ list) {
    const int lane = threadIdx.x & 63;
    const int waveId = (blockIdx.x * blockDim.x + threadIdx.x) >> 6;  // 0..1023
    int total = *cnt;
    if (total > LISTCAP) total = LISTCAP;
    for (int it = waveId; it < total; it += 1024) {
        int e = __builtin_amdgcn_readfirstlane(list[it]);
        const int row = e >> 9;
        const int old = e & 511;
        const float* xr = x + (size_t)row * DIM;
        float z[DIM];
        #pragma unroll
        for (int i = 0; i < 16; ++i) {
            float4 t4 = ((const float4*)xr)[i];
            z[4*i] = t4.x; z[4*i+1] = t4.y; z[4*i+2] = t4.z; z[4*i+3] = t4.w;
        }
        // exact xnorm (numpy AVX512 pairwise)
        float v[16];
        #pragma unroll
        for (int j = 0; j < 16; ++j) {
            float a = __fadd_rn(__fmul_rn(z[j], z[j]), __fmul_rn(z[j+16], z[j+16]));
            float b = __fadd_rn(__fmul_rn(z[j+32], z[j+32]), __fmul_rn(z[j+48], z[j+48]));
            v[j] = __fadd_rn(a, b);
        }
        float u[8];
        #pragma unroll
        for (int j = 0; j < 8; ++j) u[j] = __fadd_rn(v[j], v[j+8]);
        float c4[4];
        #pragma unroll
        for (int j = 0; j < 4; ++j) c4[j] = __fadd_rn(u[j], u[j+4]);
        const float xn = __fadd_rn(__fadd_rn(c4[0], c4[2]), __fadd_rn(c4[1], c4[3]));

        // exact sims: this lane's 8 contiguous codes, sequential-i chains.
        float acc[8];
        #pragma unroll
        for (int j = 0; j < 8; ++j) acc[j] = 0.f;
        const float* Ep = E + lane * 8;
        #pragma unroll
        for (int i = 0; i < DIM; ++i) {
            const float4 e0 = ((const float4*)(Ep + (size_t)i * KCODES))[0];
            const float4 e1 = ((const float4*)(Ep + (size_t)i * KCODES))[1];
            const float zi = z[i];
            acc[0] = __fmaf_rn(zi, e0.x, acc[0]);
            acc[1] = __fmaf_rn(zi, e0.y, acc[1]);
            acc[2] = __fmaf_rn(zi, e0.z, acc[2]);
            acc[3] = __fmaf_rn(zi, e0.w, acc[3]);
            acc[4] = __fmaf_rn(zi, e1.x, acc[4]);
            acc[5] = __fmaf_rn(zi, e1.y, acc[5]);
            acc[6] = __fmaf_rn(zi, e1.z, acc[6]);
            acc[7] = __fmaf_rn(zi, e1.w, acc[7]);
        }
        float bd = 3.4e38f; int bk = 0;
        #pragma unroll
        for (int j = 0; j < 8; ++j) {
            int k = lane * 8 + j;
            float t1 = __fadd_rn(xn, en[k]);
            float d = __fadd_rn(t1, -2.0f * acc[j]);
            if (d < bd) { bd = d; bk = k; }
        }
        #pragma unroll
        for (int off = 1; off <= 32; off <<= 1) {
            float od = __shfl_xor(bd, off, 64);
            int   ok = __shfl_xor(bk, off, 64);
            if (od < bd || (od == bd && ok < bk)) { bd = od; bk = ok; }
        }
        if (bk != old) {
            const float xl = xr[lane];
            const float qn = ET[bk * DIM + lane];
            const float qo = ET[old * DIM + lane];
            const float dn = __fadd_rn(qn, -xl);
            const float dd = __fadd_rn(qo, -xl);
            outp[(size_t)row * DIM + lane] = __fadd_rn(xl, dn);
            float dl = __fsub_rn(__fmul_rn(dn, dn), __fmul_rn(dd, dd));
            #pragma unroll
            for (int off = 32; off > 0; off >>= 1) dl += __shfl_xor(dl, off, 64);
            if (lane == 0) atomicAdd(loss, dl * (1.25f / (float)NELEM));
        }
    }
}

extern "C" void kernel_launch(void* const* d_in, const int* in_sizes, int n_in,
                              void* d_out, int out_size, void* d_ws, size_t ws_size,
                              hipStream_t stream) {
    const float* x = (const float*)d_in[0];
    const float* E = (const float*)d_in[1];
    float* out  = (float*)d_out;
    float* loss = out + NELEM;
    float* ws = (float*)d_ws;
    float* ET    = ws + WS_ET;
    float* en    = ws + WS_EN;
    float* en8   = ws + WS_EN8;
    uint4* packH = (uint4*)(ws + WS_PACKH);
    int* cnt  = (int*)(ws + WS_CNT);
    int* list = (int*)(ws + WS_LIST);

    vq_prep<<<2, 256, 0, stream>>>(E, ET, en, en8, loss, cnt);
    vq_pack<<<16, 256, 0, stream>>>(E, packH);
    vq_main<<<1024, 256, 0, stream>>>(x, ET, en8, packH, out, loss, cnt, list);
    vq_fixup<<<256, 256, 0, stream>>>(x, E, ET, en, out, loss, cnt, list);
}

// Round 6
// 239.924 us; speedup vs baseline: 1.9064x; 1.9064x over previous
//
#include <hip/hip_runtime.h>

// VectorQuantizer: x (64,64,64,64) f32, embeddings (64,512) f32
// rows N = 64^3 = 262144, D = 64, K = 512
// out: quantized_st (16777216 f32) ++ loss (1 f32)
//
// Round 6: fp16 2-term-split MFMA main (A = z_hi+z_lo fp16, B = e_hi fp16)
// + near-tie flagging (12-grid-step window) + bit-exact numpy-emulation
// fixup (verified absmax 0.0 rounds 2-5). Round-5 bug fixed: vq_fixup had
// no __launch_bounds__, so the default 1024-thread budget capped it at 64
// VGPRs -> z[64] lived in scratch -> 430 MB of HBM spill traffic. Now
// one-wave blocks with __launch_bounds__(64,1) -> VGPR cap 512, no spill.
// vq_main: register double-buffer prefetch of B-fragments.

typedef __attribute__((ext_vector_type(8))) _Float16 f16x8;
typedef __attribute__((ext_vector_type(16))) float f32x16;

#define NROWS   262144
#define DIM     64
#define KCODES  512
#define NELEM   16777216
#define LISTCAP 65536

// ws layout (float offsets)
#define WS_ET     0        // 512*64 code-major embeddings
#define WS_EN     32768    // exact enorm (numpy rounding)
#define WS_EN8    33280    // enorm + 8 (approx domain, keeps d positive)
#define WS_PACKH  33792    // uint4[4096]: e_hi fp16 B-fragments
#define WS_CNT    50176    // flag counter (int)
#define WS_LIST   50192    // flagged rows: (row<<9)|idx

union FragH { uint4 q; f16x8 v; _Float16 u[8]; };

// ---- prep: ET transpose, exact enorm (R(e*e) + sequential adds), enorm+8,
// zero loss + flag counter.
__global__ void vq_prep(const float* __restrict__ E, float* __restrict__ ET,
                        float* __restrict__ en, float* __restrict__ en8,
                        float* __restrict__ loss, int* __restrict__ cnt) {
    int k = blockIdx.x * blockDim.x + threadIdx.x;   // 0..511
    if (k == 0) *loss = 0.f;
    if (k == 1) *cnt = 0;
    float s = 0.f;
    for (int i = 0; i < DIM; ++i) {
        float v = E[i * KCODES + k];
        ET[k * DIM + i] = v;
        s = __fadd_rn(s, __fmul_rn(v, v));
    }
    en[k] = s;
    en8[k] = __fadd_rn(s, 8.0f);
}

// ---- pack e_hi (fp16 RNE) into 32x32x16 B-fragment order:
// frag id = (t*4+c)*64+lane holds B[k = c*16+(lane>>5)*8+j][n = t*32+(lane&31)]
__global__ void vq_pack(const float* __restrict__ E, uint4* __restrict__ packH) {
    const int id = blockIdx.x * 256 + threadIdx.x;   // 0..4095
    const int lane = id & 63;
    const int c = (id >> 6) & 3;
    const int t = id >> 8;
    const int n = t * 32 + (lane & 31);
    const int kb = c * 16 + (lane >> 5) * 8;
    FragH H;
    #pragma unroll
    for (int j = 0; j < 8; ++j)
        H.u[j] = (_Float16)E[(size_t)(kb + j) * KCODES + n];
    packH[id] = H.q;
}

// ---- main: 4 waves x 64 rows = 256 rows/block, grid 1024. No LDS.
// Each wave: two 32x32 M-tiles over 16 col-tiles; 16 MFMA per tile-pair.
__global__ __launch_bounds__(256)
void vq_main(const float* __restrict__ x, const float* __restrict__ ET,
             const float* __restrict__ en8, const uint4* __restrict__ packH,
             float* __restrict__ outp, float* __restrict__ loss,
             int* __restrict__ cnt, int* __restrict__ list) {
    const int tid  = threadIdx.x;
    const int wv   = tid >> 6;
    const int lane = tid & 63;
    const int h    = lane >> 5;
    const int l31  = lane & 31;
    const size_t rowbase = (size_t)blockIdx.x * 256 + (size_t)wv * 64;

    // A fragments: fp16 split z = zh + zl; A[m=lane&31][k=c*16+h*8+j]
    FragH ah[2][4], al[2][4];
    #pragma unroll
    for (int m = 0; m < 2; ++m) {
        const float* xr = x + (rowbase + m * 32 + l31) * DIM;
        #pragma unroll
        for (int c = 0; c < 4; ++c) {
            const float* xp = xr + c * 16 + h * 8;
            float4 p0 = *(const float4*)xp;
            float4 p1 = *(const float4*)(xp + 4);
            float vv[8] = {p0.x, p0.y, p0.z, p0.w, p1.x, p1.y, p1.z, p1.w};
            #pragma unroll
            for (int j = 0; j < 8; ++j) {
                _Float16 hh = (_Float16)vv[j];
                ah[m][c].u[j] = hh;
                al[m][c].u[j] = (_Float16)(vv[j] - (float)hh);
            }
        }
    }

    float en8v[16];
    #pragma unroll
    for (int t = 0; t < 16; ++t) en8v[t] = en8[t * 32 + l31];

    unsigned int b1[2][16], b2[2][16];               // per-row-slot top-2 keys
    #pragma unroll
    for (int m = 0; m < 2; ++m)
        #pragma unroll
        for (int r = 0; r < 16; ++r) { b1[m][r] = 0xFFFFFFFFu; b2[m][r] = 0xFFFFFFFFu; }

    // Register double-buffer: prefetch t+1's B-fragments before t's MFMAs.
    FragH bh[4], bn[4];
    #pragma unroll
    for (int c = 0; c < 4; ++c) bh[c].q = packH[c * 64 + lane];

    for (int t = 0; t < 16; ++t) {
        if (t < 15) {
            #pragma unroll
            for (int c = 0; c < 4; ++c)
                bn[c].q = packH[((t + 1) * 4 + c) * 64 + lane];   // L1/L2-hot
        }
        f32x16 A0, A1;
        #pragma unroll
        for (int r = 0; r < 16; ++r) { A0[r] = 0.f; A1[r] = 0.f; }
        #pragma unroll
        for (int c = 0; c < 4; ++c) {                    // z_hi * e_hi
            A0 = __builtin_amdgcn_mfma_f32_32x32x16_f16(ah[0][c].v, bh[c].v, A0, 0, 0, 0);
            A1 = __builtin_amdgcn_mfma_f32_32x32x16_f16(ah[1][c].v, bh[c].v, A1, 0, 0, 0);
        }
        #pragma unroll
        for (int c = 0; c < 4; ++c) {                    // z_lo * e_hi
            A0 = __builtin_amdgcn_mfma_f32_32x32x16_f16(al[0][c].v, bh[c].v, A0, 0, 0, 0);
            A1 = __builtin_amdgcn_mfma_f32_32x32x16_f16(al[1][c].v, bh[c].v, A1, 0, 0, 0);
        }
        // keys: d = enorm+8 - 2*sim > 0; (bits & ~511) | col sorts by dist
        const unsigned int colv = (unsigned int)(t * 32 + l31);
        #pragma unroll
        for (int r = 0; r < 16; ++r) {
            {
                float d = fmaf(-2.f, A0[r], en8v[t]);
                unsigned int key = (__float_as_uint(d) & 0xFFFFFE00u) | colv;
                unsigned int n1 = min(key, b1[0][r]);
                unsigned int mx = max(key, b1[0][r]);
                b2[0][r] = min(b2[0][r], mx);
                b1[0][r] = n1;
            }
            {
                float d = fmaf(-2.f, A1[r], en8v[t]);
                unsigned int key = (__float_as_uint(d) & 0xFFFFFE00u) | colv;
                unsigned int n1 = min(key, b1[1][r]);
                unsigned int mx = max(key, b1[1][r]);
                b2[1][r] = min(b2[1][r], mx);
                b1[1][r] = n1;
            }
        }
        #pragma unroll
        for (int c = 0; c < 4; ++c) bh[c] = bn[c];
    }

    // merge top-2 across the 32-lane half-group; C row = (r&3)+8*(r>>2)+4*h
    float lsq = 0.f;
    #pragma unroll
    for (int m = 0; m < 2; ++m) {
        #pragma unroll
        for (int r = 0; r < 16; ++r) {
            unsigned int B1 = b1[m][r], B2 = b2[m][r];
            #pragma unroll
            for (int off = 1; off <= 16; off <<= 1) {
                unsigned int o1 = (unsigned int)__shfl_xor((int)B1, off, 64);
                unsigned int o2 = (unsigned int)__shfl_xor((int)B2, off, 64);
                unsigned int n1 = min(B1, o1);
                unsigned int mx = max(B1, o1);
                B2 = min(min(B2, o2), mx);
                B1 = n1;
            }
            const int idx = (int)(B1 & 511u);
            const int rowl = (r & 3) + 8 * (r >> 2) + 4 * h;
            const size_t row = rowbase + m * 32 + rowl;
            // 12-step window: min coverage (12-2)*2.44e-4 = 2.44e-3 >
            // 1.8e-3 worst-case differential approx error.
            if (l31 == 0 &&
                ((B2 & 0xFFFFFE00u) - (B1 & 0xFFFFFE00u)) <= (12u << 9)) {
                int slot = atomicAdd(cnt, 1);
                if (slot < LISTCAP)
                    list[slot] = (int)(((unsigned int)row << 9) | (unsigned int)idx);
            }
            // out = R(x + R(q - x)); 32 lanes x 2 cols cover the row
            const float2 q2 = ((const float2*)(ET + idx * DIM))[l31];
            const float2 x2 = ((const float2*)(x + row * DIM))[l31];
            float d0 = __fadd_rn(q2.x, -x2.x);
            float d1 = __fadd_rn(q2.y, -x2.y);
            float2 o;
            o.x = __fadd_rn(x2.x, d0);
            o.y = __fadd_rn(x2.y, d1);
            ((float2*)(outp + row * DIM))[l31] = o;
            lsq = fmaf(d0, d0, lsq);
            lsq = fmaf(d1, d1, lsq);
        }
    }
    #pragma unroll
    for (int off = 32; off > 0; off >>= 1) lsq += __shfl_xor(lsq, off, 64);
    if (lane == 0) atomicAdd(loss, lsq * (1.25f / (float)NELEM));
}

// ---- fixup: ONE WAVE PER BLOCK, __launch_bounds__(64,1) -> VGPR cap 512,
// z[] + acc[] fully in registers (round-5's 64-VGPR default budget forced
// scratch spill -> 430 MB HBM traffic). Full bit-exact numpy emulation over
// all 512 codes (8 codes/lane, sequential-i FMA chains), rewrite if changed.
__global__ __launch_bounds__(64, 1)
void vq_fixup(const float* __restrict__ x, const float* __restrict__ E,
              const float* __restrict__ ET, const float* __restrict__ en,
              float* __restrict__ outp, float* __restrict__ loss,
              const int* __restrict__ cnt, const int* __restrict__ list) {
    const int lane = threadIdx.x;        // one wave per block
    int total = *cnt;
    if (total > LISTCAP) total = LISTCAP;
    for (int it = blockIdx.x; it < total; it += 2048) {
        int e = __builtin_amdgcn_readfirstlane(list[it]);
        const int row = e >> 9;
        const int old = e & 511;
        const float* xr = x + (size_t)row * DIM;
        float z[DIM];
        #pragma unroll
        for (int i = 0; i < 16; ++i) {
            float4 t4 = ((const float4*)xr)[i];
            z[4*i] = t4.x; z[4*i+1] = t4.y; z[4*i+2] = t4.z; z[4*i+3] = t4.w;
        }
        // exact xnorm (numpy AVX512 pairwise)
        float v[16];
        #pragma unroll
        for (int j = 0; j < 16; ++j) {
            float a = __fadd_rn(__fmul_rn(z[j], z[j]), __fmul_rn(z[j+16], z[j+16]));
            float b = __fadd_rn(__fmul_rn(z[j+32], z[j+32]), __fmul_rn(z[j+48], z[j+48]));
            v[j] = __fadd_rn(a, b);
        }
        float u[8];
        #pragma unroll
        for (int j = 0; j < 8; ++j) u[j] = __fadd_rn(v[j], v[j+8]);
        float c4[4];
        #pragma unroll
        for (int j = 0; j < 4; ++j) c4[j] = __fadd_rn(u[j], u[j+4]);
        const float xn = __fadd_rn(__fadd_rn(c4[0], c4[2]), __fadd_rn(c4[1], c4[3]));

        // exact sims: this lane's 8 contiguous codes, sequential-i chains.
        float acc[8];
        #pragma unroll
        for (int j = 0; j < 8; ++j) acc[j] = 0.f;
        const float* Ep = E + lane * 8;
        #pragma unroll
        for (int i = 0; i < DIM; ++i) {
            const float4 e0 = ((const float4*)(Ep + (size_t)i * KCODES))[0];
            const float4 e1 = ((const float4*)(Ep + (size_t)i * KCODES))[1];
            const float zi = z[i];
            acc[0] = __fmaf_rn(zi, e0.x, acc[0]);
            acc[1] = __fmaf_rn(zi, e0.y, acc[1]);
            acc[2] = __fmaf_rn(zi, e0.z, acc[2]);
            acc[3] = __fmaf_rn(zi, e0.w, acc[3]);
            acc[4] = __fmaf_rn(zi, e1.x, acc[4]);
            acc[5] = __fmaf_rn(zi, e1.y, acc[5]);
            acc[6] = __fmaf_rn(zi, e1.z, acc[6]);
            acc[7] = __fmaf_rn(zi, e1.w, acc[7]);
        }
        float bd = 3.4e38f; int bk = 0;
        #pragma unroll
        for (int j = 0; j < 8; ++j) {
            int k = lane * 8 + j;
            float t1 = __fadd_rn(xn, en[k]);
            float d = __fadd_rn(t1, -2.0f * acc[j]);
            if (d < bd) { bd = d; bk = k; }
        }
        #pragma unroll
        for (int off = 1; off <= 32; off <<= 1) {
            float od = __shfl_xor(bd, off, 64);
            int   ok = __shfl_xor(bk, off, 64);
            if (od < bd || (od == bd && ok < bk)) { bd = od; bk = ok; }
        }
        if (bk != old) {
            const float xl = xr[lane];
            const float qn = ET[bk * DIM + lane];
            const float qo = ET[old * DIM + lane];
            const float dn = __fadd_rn(qn, -xl);
            const float dd = __fadd_rn(qo, -xl);
            outp[(size_t)row * DIM + lane] = __fadd_rn(xl, dn);
            float dl = __fsub_rn(__fmul_rn(dn, dn), __fmul_rn(dd, dd));
            #pragma unroll
            for (int off = 32; off > 0; off >>= 1) dl += __shfl_xor(dl, off, 64);
            if (lane == 0) atomicAdd(loss, dl * (1.25f / (float)NELEM));
        }
    }
}

extern "C" void kernel_launch(void* const* d_in, const int* in_sizes, int n_in,
                              void* d_out, int out_size, void* d_ws, size_t ws_size,
                              hipStream_t stream) {
    const float* x = (const float*)d_in[0];
    const float* E = (const float*)d_in[1];
    float* out  = (float*)d_out;
    float* loss = out + NELEM;
    float* ws = (float*)d_ws;
    float* ET    = ws + WS_ET;
    float* en    = ws + WS_EN;
    float* en8   = ws + WS_EN8;
    uint4* packH = (uint4*)(ws + WS_PACKH);
    int* cnt  = (int*)(ws + WS_CNT);
    int* list = (int*)(ws + WS_LIST);

    vq_prep<<<2, 256, 0, stream>>>(E, ET, en, en8, loss, cnt);
    vq_pack<<<16, 256, 0, stream>>>(E, packH);
    vq_main<<<1024, 256, 0, stream>>>(x, ET, en8, packH, out, loss, cnt, list);
    vq_fixup<<<2048, 64, 0, stream>>>(x, E, ET, en, out, loss, cnt, list);
}